// Round 3
// baseline (486.241 us; speedup 1.0000x reference)
//
#include <hip/hip_runtime.h>
#include <math.h>

#define T_DIM 1024
#define B_DIM 16
#define C_DIM 1024
#define H_DIM 16
#define K_TAPS 7
#define PAD_LEFT 3
#define OUT_DIM 1024
#define M_DIM (T_DIM * B_DIM)   // 16384
#define HK 112
#define HKP 128
#define KD 1024                 // K for all GEMMs
#define NT (KD / 64)            // 16 K-tiles for 256^2 kernel

typedef __attribute__((ext_vector_type(8))) short bf16x8;
typedef __attribute__((ext_vector_type(4))) float f32x4;

__device__ __forceinline__ ushort f2bf(float f) {
    union { float f; unsigned u; } v; v.f = f;
    unsigned u = v.u;
    u += 0x7fffu + ((u >> 16) & 1u);
    return (ushort)(u >> 16);
}
__device__ __forceinline__ float bf2f(ushort h) {
    union { unsigned u; float f; } v; v.u = ((unsigned)h) << 16;
    return v.f;
}

// ---------------------------------------------------------------------------
// fp32 -> bf16 convert, 8 elems/thread
// ---------------------------------------------------------------------------
__global__ __launch_bounds__(256) void cvt_bf16x8(const float* __restrict__ in,
                                                  ushort* __restrict__ out,
                                                  int n8) {
    int i = blockIdx.x * blockDim.x + threadIdx.x;
    if (i >= n8) return;
    const float4* p = (const float4*)in;
    float4 a = p[2 * i], b = p[2 * i + 1];
    uint4 o;
    o.x = (unsigned)f2bf(a.x) | ((unsigned)f2bf(a.y) << 16);
    o.y = (unsigned)f2bf(a.z) | ((unsigned)f2bf(a.w) << 16);
    o.z = (unsigned)f2bf(b.x) | ((unsigned)f2bf(b.y) << 16);
    o.w = (unsigned)f2bf(b.z) | ((unsigned)f2bf(b.w) << 16);
    ((uint4*)out)[i] = o;
}

// ---------------------------------------------------------------------------
// Transpose + convert: Wt[n][k] (bf16) = W[k][n] (fp32). n >= N -> 0 pad.
// ---------------------------------------------------------------------------
__global__ void transpose_cvt(const float* __restrict__ W,
                              ushort* __restrict__ Wt,
                              int Kd, int N, int Npad) {
    __shared__ float tile[32][33];
    int n0 = blockIdx.x * 32, k0 = blockIdx.y * 32;
    int tx = threadIdx.x, ty = threadIdx.y;
#pragma unroll
    for (int j = 0; j < 4; ++j) {
        int k = k0 + ty * 4 + j;
        int n = n0 + tx;
        tile[ty * 4 + j][tx] = (n < N) ? W[(size_t)k * N + n] : 0.f;
    }
    __syncthreads();
#pragma unroll
    for (int j = 0; j < 4; ++j) {
        int n = n0 + ty * 4 + j;
        if (n < Npad)
            Wt[(size_t)n * Kd + k0 + tx] = f2bf(tile[tx][ty * 4 + j]);
    }
}

// ---------------------------------------------------------------------------
// 256x256 bf16 MFMA GEMM, BK=64, 512 threads (8 waves 2Mx4N), dbuf LDS,
// counted-vmcnt pipeline + st_16x32 swizzle + setprio + XCD-bijective swizzle.
// C[M,N] = A[M,K] @ Bt[N,K]^T + bias.  M=16384, N=1024, K=1024 fixed.
// ---------------------------------------------------------------------------
#define MFMA_BLOCK(AF, BF)                                                    \
    __builtin_amdgcn_s_setprio(1);                                            \
    _Pragma("unroll")                                                         \
    for (int m = 0; m < 8; ++m)                                               \
        _Pragma("unroll")                                                     \
        for (int n = 0; n < 4; ++n)                                           \
            acc[m][n] = __builtin_amdgcn_mfma_f32_16x16x32_bf16(              \
                AF[m], BF[n], acc[m][n], 0, 0, 0);                            \
    __builtin_amdgcn_s_setprio(0);

template <bool OUT_BF16>
__global__ __launch_bounds__(512, 2) void gemm256(
    const ushort* __restrict__ A, const ushort* __restrict__ Bt,
    const float* __restrict__ bias, void* __restrict__ Cp, int ldc) {
    __shared__ ushort Ab[2][256 * 64];
    __shared__ ushort Bb[2][256 * 64];

    const int tid  = threadIdx.x;
    const int lane = tid & 63;
    const int wid  = tid >> 6;
    const int wr = wid >> 2;        // 0..1  (M half, 128 rows)
    const int wc = wid & 3;         // 0..3  (N quarter, 64 cols)
    const int fr = lane & 15;
    const int fq = lane >> 4;

    // bijective XCD swizzle: 256 wgs, 32 consecutive per XCD
    const int orig = blockIdx.x;
    const int nid  = (orig & 7) * 32 + (orig >> 3);
    const int bm = (nid >> 2) * 256;
    const int bn = (nid & 3) * 256;

    // --- staging precompute: linear LDS dest + inverse-swizzled global src ---
    size_t srcA[4], srcB[4];
    int ldsW[4];
#pragma unroll
    for (int i = 0; i < 4; ++i) {
        int c   = i * 512 + wid * 64 + lane;       // 16B chunk id, 0..2047
        int lin = c * 16;                          // linear byte in tile
        int p   = lin ^ (((lin >> 9) & 1) << 5);   // st_16x32 involution
        int row = p >> 7;                          // 0..255
        int kb  = p & 127;                         // byte within row
        srcA[i] = (size_t)(bm + row) * KD + (kb >> 1);
        srcB[i] = (size_t)(bn + row) * KD + (kb >> 1);
        ldsW[i] = (i * 512 + wid * 64) * 8;        // wave-uniform base (ushorts)
    }

    // --- read-side swizzled fragment bases (ushort offsets) ---
    int baseA[8], baseB[4];
#pragma unroll
    for (int m = 0; m < 8; ++m) {
        int row = wr * 128 + m * 16 + fr;
        int swz = ((row >> 2) & 1) << 5;
        baseA[m] = row * 64 + (((fq * 16) ^ swz) >> 1);
    }
#pragma unroll
    for (int n = 0; n < 4; ++n) {
        int row = wc * 64 + n * 16 + fr;
        int swz = ((row >> 2) & 1) << 5;
        baseB[n] = row * 64 + (((fq * 16) ^ swz) >> 1);
    }

    f32x4 acc[8][4];
#pragma unroll
    for (int m = 0; m < 8; ++m)
#pragma unroll
        for (int n = 0; n < 4; ++n) acc[m][n] = (f32x4){0.f, 0.f, 0.f, 0.f};

    auto stage = [&](int buf, int koff) {
#pragma unroll
        for (int i = 0; i < 4; ++i) {
            __builtin_amdgcn_global_load_lds(
                (const __attribute__((address_space(1))) void*)(A + srcA[i] + koff),
                (__attribute__((address_space(3))) void*)(&Ab[buf][ldsW[i]]),
                16, 0, 0);
            __builtin_amdgcn_global_load_lds(
                (const __attribute__((address_space(1))) void*)(Bt + srcB[i] + koff),
                (__attribute__((address_space(3))) void*)(&Bb[buf][ldsW[i]]),
                16, 0, 0);
        }
    };

    // prologue: tiles 0 and 1 in flight; wait only for tile 0 (vmcnt(8))
    stage(0, 0);
    stage(1, 64);
    asm volatile("s_waitcnt vmcnt(8)" ::: "memory");
    __builtin_amdgcn_sched_barrier(0);
    __builtin_amdgcn_s_barrier();

#pragma unroll 1
    for (int t = 0; t < NT; ++t) {
        const int cur = t & 1;
        const ushort* Ac = &Ab[cur][0];
        const ushort* Bc = &Bb[cur][0];
        bf16x8 a0[8], b0[4], a1[8], b1[4];
#pragma unroll
        for (int m = 0; m < 8; ++m) a0[m] = *(const bf16x8*)(Ac + baseA[m]);
#pragma unroll
        for (int n = 0; n < 4; ++n) b0[n] = *(const bf16x8*)(Bc + baseB[n]);

        MFMA_BLOCK(a0, b0)              // ksub0: k = t*64 .. +31

#pragma unroll
        for (int m = 0; m < 8; ++m) a1[m] = *(const bf16x8*)(Ac + baseA[m] + 32);
#pragma unroll
        for (int n = 0; n < 4; ++n) b1[n] = *(const bf16x8*)(Bc + baseB[n] + 32);

        if (t < NT - 1) {
            // all reads of buf[cur] complete -> safe for others to overwrite
            asm volatile("s_waitcnt lgkmcnt(0)" ::: "memory");
            __builtin_amdgcn_sched_barrier(0);
            __builtin_amdgcn_s_barrier();
            if (t < NT - 2) stage(cur, (t + 2) * 64);

            MFMA_BLOCK(a1, b1)          // ksub1, overlaps staging

            if (t < NT - 2) {
                asm volatile("s_waitcnt vmcnt(8)" ::: "memory");  // tile t+1 landed
            } else {
                asm volatile("s_waitcnt vmcnt(0)" ::: "memory");
            }
            __builtin_amdgcn_sched_barrier(0);
            __builtin_amdgcn_s_barrier();
        } else {
            MFMA_BLOCK(a1, b1)
        }
    }

    // epilogue: C/D layout col=lane&15, row=(lane>>4)*4+r
#pragma unroll
    for (int n = 0; n < 4; ++n) {
        int col = bn + wc * 64 + n * 16 + fr;
        float bv = bias[col];
#pragma unroll
        for (int m = 0; m < 8; ++m) {
#pragma unroll
            for (int r = 0; r < 4; ++r) {
                int row = bm + wr * 128 + m * 16 + fq * 4 + r;
                float v = acc[m][n][r] + bv;
                if (OUT_BF16)
                    ((ushort*)Cp)[(size_t)row * ldc + col] = f2bf(v);
                else
                    ((float*)Cp)[(size_t)row * ldc + col] = v;
            }
        }
    }
}

// ---------------------------------------------------------------------------
// m97-style 128x128 GEMM kept for the small N=112 GEMM2
// ---------------------------------------------------------------------------
template <bool OUT_BF16, bool NGUARD>
__global__ __launch_bounds__(256) void gemm_mfma(const ushort* __restrict__ A,
                                                 const ushort* __restrict__ Bt,
                                                 const float* __restrict__ bias,
                                                 void* __restrict__ Cp,
                                                 int Kd, int N, int ldc) {
    __shared__ ushort Als[128 * 32];
    __shared__ ushort Bls[128 * 32];
    const int tid  = threadIdx.x;
    const int lane = tid & 63;
    const int wid  = tid >> 6;
    const int wr = wid >> 1, wc = wid & 1;
    const int bm = blockIdx.y * 128, bn = blockIdx.x * 128;
    const int fq = lane >> 4, fr = lane & 15;

    f32x4 acc[4][4];
#pragma unroll
    for (int m = 0; m < 4; ++m)
#pragma unroll
        for (int n = 0; n < 4; ++n) acc[m][n] = (f32x4){0.f, 0.f, 0.f, 0.f};

    const int c0 = wid * 128 + lane;
    const int c1 = c0 + 64;
    const int r0 = c0 >> 2, o0 = (c0 & 3) * 8;
    const int r1 = c1 >> 2, o1 = (c1 & 3) * 8;

    for (int k0 = 0; k0 < Kd; k0 += 32) {
        __builtin_amdgcn_global_load_lds(
            (const __attribute__((address_space(1))) void*)&A[(size_t)(bm + r0) * Kd + k0 + o0],
            (__attribute__((address_space(3))) void*)&Als[(wid * 2 + 0) * 512], 16, 0, 0);
        __builtin_amdgcn_global_load_lds(
            (const __attribute__((address_space(1))) void*)&A[(size_t)(bm + r1) * Kd + k0 + o1],
            (__attribute__((address_space(3))) void*)&Als[(wid * 2 + 1) * 512], 16, 0, 0);
        __builtin_amdgcn_global_load_lds(
            (const __attribute__((address_space(1))) void*)&Bt[(size_t)(bn + r0) * Kd + k0 + o0],
            (__attribute__((address_space(3))) void*)&Bls[(wid * 2 + 0) * 512], 16, 0, 0);
        __builtin_amdgcn_global_load_lds(
            (const __attribute__((address_space(1))) void*)&Bt[(size_t)(bn + r1) * Kd + k0 + o1],
            (__attribute__((address_space(3))) void*)&Bls[(wid * 2 + 1) * 512], 16, 0, 0);
        __syncthreads();

        bf16x8 af[4], bfr[4];
#pragma unroll
        for (int m = 0; m < 4; ++m)
            af[m] = *(const bf16x8*)&Als[(wr * 64 + m * 16 + fr) * 32 + fq * 8];
#pragma unroll
        for (int n = 0; n < 4; ++n)
            bfr[n] = *(const bf16x8*)&Bls[(wc * 64 + n * 16 + fr) * 32 + fq * 8];
#pragma unroll
        for (int m = 0; m < 4; ++m)
#pragma unroll
            for (int n = 0; n < 4; ++n)
                acc[m][n] = __builtin_amdgcn_mfma_f32_16x16x32_bf16(
                    af[m], bfr[n], acc[m][n], 0, 0, 0);
        __syncthreads();
    }

#pragma unroll
    for (int m = 0; m < 4; ++m) {
#pragma unroll
        for (int n = 0; n < 4; ++n) {
            int col = bn + wc * 64 + n * 16 + fr;
            if (NGUARD && col >= N) continue;
            float bv = bias[col];
#pragma unroll
            for (int r = 0; r < 4; ++r) {
                int row = bm + wr * 64 + m * 16 + fq * 4 + r;
                float v = acc[m][n][r] + bv;
                if (OUT_BF16)
                    ((ushort*)Cp)[(size_t)row * ldc + col] = f2bf(v);
                else
                    ((float*)Cp)[(size_t)row * ldc + col] = v;
            }
        }
    }
}

// ---------------------------------------------------------------------------
__global__ void softmax7(const float* __restrict__ q, float* __restrict__ w,
                         int rows) {
    int r = blockIdx.x * blockDim.x + threadIdx.x;
    if (r >= rows) return;
    const float* p = q + (size_t)r * K_TAPS;
    float mx = p[0];
#pragma unroll
    for (int k = 1; k < K_TAPS; ++k) mx = fmaxf(mx, p[k]);
    float e[K_TAPS], s = 0.f;
#pragma unroll
    for (int k = 0; k < K_TAPS; ++k) { e[k] = expf(p[k] - mx); s += e[k]; }
    float inv = 1.f / s;
    float* o = w + (size_t)r * K_TAPS;
#pragma unroll
    for (int k = 0; k < K_TAPS; ++k) o[k] = e[k] * inv;
}

// ---------------------------------------------------------------------------
__global__ __launch_bounds__(256) void dynconv_bf16(const ushort* __restrict__ h,
                                                    const float* __restrict__ w,
                                                    const float* __restrict__ cbias,
                                                    ushort* __restrict__ out) {
    const int m = blockIdx.x;
    const int t = m >> 4;
    const int b = m & 15;

    __shared__ float wsm[HK];
    if (threadIdx.x < HK)
        wsm[threadIdx.x] = w[(size_t)m * HK + threadIdx.x];
    __syncthreads();

    const int c = threadIdx.x * 4;
    const int hh = c >> 6;

    float4 bias = *(const float4*)&cbias[c];
    float a0 = bias.x, a1 = bias.y, a2 = bias.z, a3 = bias.w;

#pragma unroll
    for (int k = 0; k < K_TAPS; ++k) {
        int tt = t + k - PAD_LEFT;
        if (tt < 0 || tt >= T_DIM) continue;
        ushort4 hv = *(const ushort4*)&h[((size_t)tt * B_DIM + b) * C_DIM + c];
        float wk = wsm[hh * K_TAPS + k];
        a0 = fmaf(bf2f(hv.x), wk, a0);
        a1 = fmaf(bf2f(hv.y), wk, a1);
        a2 = fmaf(bf2f(hv.z), wk, a2);
        a3 = fmaf(bf2f(hv.w), wk, a3);
    }
    ushort4 o;
    o.x = f2bf(a0); o.y = f2bf(a1); o.z = f2bf(a2); o.w = f2bf(a3);
    *(ushort4*)&out[(size_t)m * C_DIM + c] = o;
}

// ---------------------------------------------------------------------------
extern "C" void kernel_launch(void* const* d_in, const int* in_sizes, int n_in,
                              void* d_out, int out_size, void* d_ws,
                              size_t ws_size, hipStream_t stream) {
    const float* x     = (const float*)d_in[0];
    const float* W1    = (const float*)d_in[1];
    const float* b1    = (const float*)d_in[2];
    const float* Wq    = (const float*)d_in[3];
    const float* bq    = (const float*)d_in[4];
    const float* cbias = (const float*)d_in[5];
    const float* W2    = (const float*)d_in[6];
    const float* b2    = (const float*)d_in[7];
    float* out = (float*)d_out;

    ushort* xb    = (ushort*)d_ws;
    ushort* hb    = xb    + (size_t)M_DIM * C_DIM;
    ushort* convb = hb    + (size_t)M_DIM * C_DIM;
    ushort* W1t   = convb + (size_t)M_DIM * C_DIM;
    ushort* W2t   = W1t   + (size_t)C_DIM * C_DIM;
    ushort* Wqt   = W2t   + (size_t)C_DIM * OUT_DIM;
    float*  q     = (float*)(Wqt + (size_t)HKP * C_DIM);

    cvt_bf16x8<<<dim3(M_DIM * C_DIM / 8 / 256), dim3(256), 0, stream>>>(
        x, xb, M_DIM * C_DIM / 8);
    transpose_cvt<<<dim3(C_DIM / 32, C_DIM / 32), dim3(32, 8), 0, stream>>>(
        W1, W1t, C_DIM, C_DIM, C_DIM);
    transpose_cvt<<<dim3(HKP / 32, C_DIM / 32), dim3(32, 8), 0, stream>>>(
        Wq, Wqt, C_DIM, HK, HKP);
    transpose_cvt<<<dim3(OUT_DIM / 32, C_DIM / 32), dim3(32, 8), 0, stream>>>(
        W2, W2t, C_DIM, OUT_DIM, OUT_DIM);

    // 1) h = bf16(x @ W1 + b1)   [256 wgs, 512 thr]
    gemm256<true><<<dim3(256), dim3(512), 0, stream>>>(xb, W1t, b1, hb, C_DIM);

    // 2) q = h @ Wq + bq   [16384 x 112]
    gemm_mfma<false, true>
        <<<dim3(1, M_DIM / 128), dim3(256), 0, stream>>>(
            hb, Wqt, bq, q, C_DIM, HK, HK);

    // 3) softmax over taps
    softmax7<<<dim3((M_DIM * H_DIM + 255) / 256), dim3(256), 0, stream>>>(
        q, q, M_DIM * H_DIM);

    // 4) conv = bf16(dynconv(h, w) + conv_bias)
    dynconv_bf16<<<dim3(M_DIM), dim3(256), 0, stream>>>(hb, q, cbias, convb);

    // 5) out = conv @ W2 + b2
    gemm256<false><<<dim3(256), dim3(512), 0, stream>>>(convb, W2t, b2, out,
                                                        OUT_DIM);
}

// Round 4
// 443.494 us; speedup vs baseline: 1.0964x; 1.0964x over previous
//
#include <hip/hip_runtime.h>
#include <math.h>

#define T_DIM 1024
#define B_DIM 16
#define C_DIM 1024
#define H_DIM 16
#define K_TAPS 7
#define PAD_LEFT 3
#define OUT_DIM 1024
#define M_DIM (T_DIM * B_DIM)   // 16384
#define HK 112
#define HKP 128
#define KD 1024
#define NT (KD / 64)            // 16 K-tiles for 256^2 kernel

typedef __attribute__((ext_vector_type(8))) short bf16x8;
typedef __attribute__((ext_vector_type(4))) float f32x4;

__device__ __forceinline__ ushort f2bf(float f) {
    union { float f; unsigned u; } v; v.f = f;
    unsigned u = v.u;
    u += 0x7fffu + ((u >> 16) & 1u);
    return (ushort)(u >> 16);
}
__device__ __forceinline__ float bf2f(ushort h) {
    union { unsigned u; float f; } v; v.u = ((unsigned)h) << 16;
    return v.f;
}

// ---------------------------------------------------------------------------
__global__ __launch_bounds__(256) void cvt_bf16x8(const float* __restrict__ in,
                                                  ushort* __restrict__ out,
                                                  int n8) {
    int i = blockIdx.x * blockDim.x + threadIdx.x;
    if (i >= n8) return;
    const float4* p = (const float4*)in;
    float4 a = p[2 * i], b = p[2 * i + 1];
    uint4 o;
    o.x = (unsigned)f2bf(a.x) | ((unsigned)f2bf(a.y) << 16);
    o.y = (unsigned)f2bf(a.z) | ((unsigned)f2bf(a.w) << 16);
    o.z = (unsigned)f2bf(b.x) | ((unsigned)f2bf(b.y) << 16);
    o.w = (unsigned)f2bf(b.z) | ((unsigned)f2bf(b.w) << 16);
    ((uint4*)out)[i] = o;
}

// ---------------------------------------------------------------------------
__global__ void transpose_cvt(const float* __restrict__ W,
                              ushort* __restrict__ Wt,
                              int Kd, int N, int Npad) {
    __shared__ float tile[32][33];
    int n0 = blockIdx.x * 32, k0 = blockIdx.y * 32;
    int tx = threadIdx.x, ty = threadIdx.y;
#pragma unroll
    for (int j = 0; j < 4; ++j) {
        int k = k0 + ty * 4 + j;
        int n = n0 + tx;
        tile[ty * 4 + j][tx] = (n < N) ? W[(size_t)k * N + n] : 0.f;
    }
    __syncthreads();
#pragma unroll
    for (int j = 0; j < 4; ++j) {
        int n = n0 + ty * 4 + j;
        if (n < Npad)
            Wt[(size_t)n * Kd + k0 + tx] = f2bf(tile[tx][ty * 4 + j]);
    }
}

// ---------------------------------------------------------------------------
// 256x256 bf16 MFMA GEMM, BK=64, 512 threads (8 waves 2Mx4N), dbuf LDS,
// counted-vmcnt pipeline + st_16x32 swizzle + setprio + XCD-bijective swizzle.
// Quadrant-phased MFMA to keep live fragments at 12 (48 VGPR) -> no spill.
// ---------------------------------------------------------------------------
#define MFMA_HALF(AF, BF, MOFF)                                               \
    __builtin_amdgcn_s_setprio(1);                                            \
    _Pragma("unroll")                                                         \
    for (int m = 0; m < 4; ++m)                                               \
        _Pragma("unroll")                                                     \
        for (int n = 0; n < 4; ++n)                                           \
            acc[m + MOFF][n] = __builtin_amdgcn_mfma_f32_16x16x32_bf16(       \
                AF[m], BF[n], acc[m + MOFF][n], 0, 0, 0);                     \
    __builtin_amdgcn_s_setprio(0);

template <bool OUT_BF16>
__global__ __launch_bounds__(512) void gemm256(
    const ushort* __restrict__ A, const ushort* __restrict__ Bt,
    const float* __restrict__ bias, void* __restrict__ Cp, int ldc) {
    __shared__ ushort Ab[2][256 * 64];
    __shared__ ushort Bb[2][256 * 64];

    const int tid  = threadIdx.x;
    const int lane = tid & 63;
    const int wid  = tid >> 6;
    const int wr = wid >> 2;        // 0..1  (M half, 128 rows)
    const int wc = wid & 3;         // 0..3  (N quarter, 64 cols)
    const int fr = lane & 15;
    const int fq = lane >> 4;

    // bijective XCD swizzle: 256 wgs, 32 consecutive per XCD
    const int orig = blockIdx.x;
    const int nid  = (orig & 7) * 32 + (orig >> 3);
    const int bm = (nid >> 2) * 256;
    const int bn = (nid & 3) * 256;

    // staging: linear LDS dest + inverse-swizzled global src (rule #21)
    size_t srcA[4], srcB[4];
    int ldsW[4];
#pragma unroll
    for (int i = 0; i < 4; ++i) {
        int c   = i * 512 + wid * 64 + lane;       // 16B chunk id, 0..2047
        int lin = c * 16;                          // linear byte in tile
        int p   = lin ^ (((lin >> 9) & 1) << 5);   // st_16x32 involution
        int row = p >> 7;
        int kb  = p & 127;
        srcA[i] = (size_t)(bm + row) * KD + (kb >> 1);
        srcB[i] = (size_t)(bn + row) * KD + (kb >> 1);
        ldsW[i] = (i * 512 + wid * 64) * 8;
    }

    // read-side swizzled fragment bases (ushort offsets)
    int baseA[8], baseB[4];
#pragma unroll
    for (int m = 0; m < 8; ++m) {
        int row = wr * 128 + m * 16 + fr;
        int swz = ((row >> 2) & 1) << 5;
        baseA[m] = row * 64 + (((fq * 16) ^ swz) >> 1);
    }
#pragma unroll
    for (int n = 0; n < 4; ++n) {
        int row = wc * 64 + n * 16 + fr;
        int swz = ((row >> 2) & 1) << 5;
        baseB[n] = row * 64 + (((fq * 16) ^ swz) >> 1);
    }

    f32x4 acc[8][4];
#pragma unroll
    for (int m = 0; m < 8; ++m)
#pragma unroll
        for (int n = 0; n < 4; ++n) acc[m][n] = (f32x4){0.f, 0.f, 0.f, 0.f};

    auto stage = [&](int buf, int koff) {
#pragma unroll
        for (int i = 0; i < 4; ++i) {
            __builtin_amdgcn_global_load_lds(
                (const __attribute__((address_space(1))) void*)(A + srcA[i] + koff),
                (__attribute__((address_space(3))) void*)(&Ab[buf][ldsW[i]]),
                16, 0, 0);
            __builtin_amdgcn_global_load_lds(
                (const __attribute__((address_space(1))) void*)(Bt + srcB[i] + koff),
                (__attribute__((address_space(3))) void*)(&Bb[buf][ldsW[i]]),
                16, 0, 0);
        }
    };

    // prologue: tiles 0 and 1 in flight; wait only for tile 0
    stage(0, 0);
    stage(1, 64);
    asm volatile("s_waitcnt vmcnt(8)" ::: "memory");
    __builtin_amdgcn_sched_barrier(0);
    __builtin_amdgcn_s_barrier();

#pragma unroll 1
    for (int t = 0; t < NT; ++t) {
        const int cur = t & 1;
        const ushort* Ac = &Ab[cur][0];
        const ushort* Bc = &Bb[cur][0];

        // ---- ksub0 (k = t*64 .. +31), two M-half phases sharing b0 ----
        {
            bf16x8 b0[4], aA[4], aB[4];
#pragma unroll
            for (int n = 0; n < 4; ++n) b0[n] = *(const bf16x8*)(Bc + baseB[n]);
#pragma unroll
            for (int m = 0; m < 4; ++m) aA[m] = *(const bf16x8*)(Ac + baseA[m]);
            MFMA_HALF(aA, b0, 0)
#pragma unroll
            for (int m = 0; m < 4; ++m) aB[m] = *(const bf16x8*)(Ac + baseA[m + 4]);
            MFMA_HALF(aB, b0, 4)
        }

        // ---- ksub1 reads (all remaining reads from buf[cur]) ----
        bf16x8 b1[4], cA[4], cB[4];
#pragma unroll
        for (int n = 0; n < 4; ++n) b1[n] = *(const bf16x8*)(Bc + baseB[n] + 32);
#pragma unroll
        for (int m = 0; m < 4; ++m) cA[m] = *(const bf16x8*)(Ac + baseA[m] + 32);
#pragma unroll
        for (int m = 0; m < 4; ++m) cB[m] = *(const bf16x8*)(Ac + baseA[m + 4] + 32);

        if (t < NT - 1) {
            // all reads of buf[cur] complete -> safe to overwrite
            asm volatile("s_waitcnt lgkmcnt(0)" ::: "memory");
            __builtin_amdgcn_sched_barrier(0);
            __builtin_amdgcn_s_barrier();
            if (t < NT - 2) stage(cur, (t + 2) * 64);

            MFMA_HALF(cA, b1, 0)
            MFMA_HALF(cB, b1, 4)

            if (t < NT - 2) {
                asm volatile("s_waitcnt vmcnt(8)" ::: "memory");  // tile t+1 landed
            } else {
                asm volatile("s_waitcnt vmcnt(0)" ::: "memory");
            }
            __builtin_amdgcn_sched_barrier(0);
            __builtin_amdgcn_s_barrier();
        } else {
            MFMA_HALF(cA, b1, 0)
            MFMA_HALF(cB, b1, 4)
        }
    }

    // epilogue: C/D layout col=lane&15, row=(lane>>4)*4+r
#pragma unroll
    for (int n = 0; n < 4; ++n) {
        int col = bn + wc * 64 + n * 16 + fr;
        float bv = bias[col];
#pragma unroll
        for (int m = 0; m < 8; ++m) {
#pragma unroll
            for (int r = 0; r < 4; ++r) {
                int row = bm + wr * 128 + m * 16 + fq * 4 + r;
                float v = acc[m][n][r] + bv;
                if (OUT_BF16)
                    ((ushort*)Cp)[(size_t)row * ldc + col] = f2bf(v);
                else
                    ((float*)Cp)[(size_t)row * ldc + col] = v;
            }
        }
    }
}

// ---------------------------------------------------------------------------
// m97-style 128x128 GEMM for the small N=112 GEMM2
// ---------------------------------------------------------------------------
template <bool OUT_BF16, bool NGUARD>
__global__ __launch_bounds__(256) void gemm_mfma(const ushort* __restrict__ A,
                                                 const ushort* __restrict__ Bt,
                                                 const float* __restrict__ bias,
                                                 void* __restrict__ Cp,
                                                 int Kd, int N, int ldc) {
    __shared__ ushort Als[128 * 32];
    __shared__ ushort Bls[128 * 32];
    const int tid  = threadIdx.x;
    const int lane = tid & 63;
    const int wid  = tid >> 6;
    const int wr = wid >> 1, wc = wid & 1;
    const int bm = blockIdx.y * 128, bn = blockIdx.x * 128;
    const int fq = lane >> 4, fr = lane & 15;

    f32x4 acc[4][4];
#pragma unroll
    for (int m = 0; m < 4; ++m)
#pragma unroll
        for (int n = 0; n < 4; ++n) acc[m][n] = (f32x4){0.f, 0.f, 0.f, 0.f};

    const int c0 = wid * 128 + lane;
    const int c1 = c0 + 64;
    const int r0 = c0 >> 2, o0 = (c0 & 3) * 8;
    const int r1 = c1 >> 2, o1 = (c1 & 3) * 8;

    for (int k0 = 0; k0 < Kd; k0 += 32) {
        __builtin_amdgcn_global_load_lds(
            (const __attribute__((address_space(1))) void*)&A[(size_t)(bm + r0) * Kd + k0 + o0],
            (__attribute__((address_space(3))) void*)&Als[(wid * 2 + 0) * 512], 16, 0, 0);
        __builtin_amdgcn_global_load_lds(
            (const __attribute__((address_space(1))) void*)&A[(size_t)(bm + r1) * Kd + k0 + o1],
            (__attribute__((address_space(3))) void*)&Als[(wid * 2 + 1) * 512], 16, 0, 0);
        __builtin_amdgcn_global_load_lds(
            (const __attribute__((address_space(1))) void*)&Bt[(size_t)(bn + r0) * Kd + k0 + o0],
            (__attribute__((address_space(3))) void*)&Bls[(wid * 2 + 0) * 512], 16, 0, 0);
        __builtin_amdgcn_global_load_lds(
            (const __attribute__((address_space(1))) void*)&Bt[(size_t)(bn + r1) * Kd + k0 + o1],
            (__attribute__((address_space(3))) void*)&Bls[(wid * 2 + 1) * 512], 16, 0, 0);
        __syncthreads();

        bf16x8 af[4], bfr[4];
#pragma unroll
        for (int m = 0; m < 4; ++m)
            af[m] = *(const bf16x8*)&Als[(wr * 64 + m * 16 + fr) * 32 + fq * 8];
#pragma unroll
        for (int n = 0; n < 4; ++n)
            bfr[n] = *(const bf16x8*)&Bls[(wc * 64 + n * 16 + fr) * 32 + fq * 8];
#pragma unroll
        for (int m = 0; m < 4; ++m)
#pragma unroll
            for (int n = 0; n < 4; ++n)
                acc[m][n] = __builtin_amdgcn_mfma_f32_16x16x32_bf16(
                    af[m], bfr[n], acc[m][n], 0, 0, 0);
        __syncthreads();
    }

#pragma unroll
    for (int m = 0; m < 4; ++m) {
#pragma unroll
        for (int n = 0; n < 4; ++n) {
            int col = bn + wc * 64 + n * 16 + fr;
            if (NGUARD && col >= N) continue;
            float bv = bias[col];
#pragma unroll
            for (int r = 0; r < 4; ++r) {
                int row = bm + wr * 64 + m * 16 + fq * 4 + r;
                float v = acc[m][n][r] + bv;
                if (OUT_BF16)
                    ((ushort*)Cp)[(size_t)row * ldc + col] = f2bf(v);
                else
                    ((float*)Cp)[(size_t)row * ldc + col] = v;
            }
        }
    }
}

// ---------------------------------------------------------------------------
// Dynamic conv with fused per-head softmax over the 7 taps.
// q: raw scores [M, 112]; out[m,c] = sum_k h[..] * softmax(q[m,h])[k] + cbias
// ---------------------------------------------------------------------------
__global__ __launch_bounds__(256) void dynconv_bf16(const ushort* __restrict__ h,
                                                    const float* __restrict__ q,
                                                    const float* __restrict__ cbias,
                                                    ushort* __restrict__ out) {
    const int m = blockIdx.x;
    const int t = m >> 4;
    const int b = m & 15;

    __shared__ float wsm[HK];
    if (threadIdx.x < HK)
        wsm[threadIdx.x] = q[(size_t)m * HK + threadIdx.x];
    __syncthreads();
    if (threadIdx.x < H_DIM) {
        float* p = &wsm[threadIdx.x * K_TAPS];
        float mx = p[0];
#pragma unroll
        for (int k = 1; k < K_TAPS; ++k) mx = fmaxf(mx, p[k]);
        float e[K_TAPS], s = 0.f;
#pragma unroll
        for (int k = 0; k < K_TAPS; ++k) { e[k] = __expf(p[k] - mx); s += e[k]; }
        float inv = 1.f / s;
#pragma unroll
        for (int k = 0; k < K_TAPS; ++k) p[k] = e[k] * inv;
    }
    __syncthreads();

    const int c = threadIdx.x * 4;
    const int hh = c >> 6;

    float4 bias = *(const float4*)&cbias[c];
    float a0 = bias.x, a1 = bias.y, a2 = bias.z, a3 = bias.w;

#pragma unroll
    for (int k = 0; k < K_TAPS; ++k) {
        int tt = t + k - PAD_LEFT;
        if (tt < 0 || tt >= T_DIM) continue;
        ushort4 hv = *(const ushort4*)&h[((size_t)tt * B_DIM + b) * C_DIM + c];
        float wk = wsm[hh * K_TAPS + k];
        a0 = fmaf(bf2f(hv.x), wk, a0);
        a1 = fmaf(bf2f(hv.y), wk, a1);
        a2 = fmaf(bf2f(hv.z), wk, a2);
        a3 = fmaf(bf2f(hv.w), wk, a3);
    }
    ushort4 o;
    o.x = f2bf(a0); o.y = f2bf(a1); o.z = f2bf(a2); o.w = f2bf(a3);
    *(ushort4*)&out[(size_t)m * C_DIM + c] = o;
}

// ---------------------------------------------------------------------------
extern "C" void kernel_launch(void* const* d_in, const int* in_sizes, int n_in,
                              void* d_out, int out_size, void* d_ws,
                              size_t ws_size, hipStream_t stream) {
    const float* x     = (const float*)d_in[0];
    const float* W1    = (const float*)d_in[1];
    const float* b1    = (const float*)d_in[2];
    const float* Wq    = (const float*)d_in[3];
    const float* bq    = (const float*)d_in[4];
    const float* cbias = (const float*)d_in[5];
    const float* W2    = (const float*)d_in[6];
    const float* b2    = (const float*)d_in[7];
    float* out = (float*)d_out;

    ushort* xb    = (ushort*)d_ws;
    ushort* hb    = xb    + (size_t)M_DIM * C_DIM;
    ushort* convb = hb    + (size_t)M_DIM * C_DIM;
    ushort* W1t   = convb + (size_t)M_DIM * C_DIM;
    ushort* W2t   = W1t   + (size_t)C_DIM * C_DIM;
    ushort* Wqt   = W2t   + (size_t)C_DIM * OUT_DIM;
    float*  q     = (float*)(Wqt + (size_t)HKP * C_DIM);

    cvt_bf16x8<<<dim3(M_DIM * C_DIM / 8 / 256), dim3(256), 0, stream>>>(
        x, xb, M_DIM * C_DIM / 8);
    transpose_cvt<<<dim3(C_DIM / 32, C_DIM / 32), dim3(32, 8), 0, stream>>>(
        W1, W1t, C_DIM, C_DIM, C_DIM);
    transpose_cvt<<<dim3(HKP / 32, C_DIM / 32), dim3(32, 8), 0, stream>>>(
        Wq, Wqt, C_DIM, HK, HKP);
    transpose_cvt<<<dim3(OUT_DIM / 32, C_DIM / 32), dim3(32, 8), 0, stream>>>(
        W2, W2t, C_DIM, OUT_DIM, OUT_DIM);

    // 1) h = bf16(x @ W1 + b1)
    gemm256<true><<<dim3(256), dim3(512), 0, stream>>>(xb, W1t, b1, hb, C_DIM);

    // 2) q = h @ Wq + bq   [16384 x 112]
    gemm_mfma<false, true>
        <<<dim3(1, M_DIM / 128), dim3(256), 0, stream>>>(
            hb, Wqt, bq, q, C_DIM, HK, HK);

    // 3+4) conv = bf16(dynconv(h, softmax(q)) + conv_bias)
    dynconv_bf16<<<dim3(M_DIM), dim3(256), 0, stream>>>(hb, q, cbias, convb);

    // 5) out = conv @ W2 + b2
    gemm256<false><<<dim3(256), dim3(512), 0, stream>>>(convb, W2t, b2, out,
                                                        OUT_DIM);
}

// Round 5
// 164.601 us; speedup vs baseline: 2.9541x; 2.6944x over previous
//
#include <hip/hip_runtime.h>
#include <math.h>

#define T_DIM 1024
#define B_DIM 16
#define C_DIM 1024
#define H_DIM 16
#define K_TAPS 7
#define PAD_LEFT 3
#define OUT_DIM 1024
#define M_DIM (T_DIM * B_DIM)   // 16384
#define HK 112
#define HKP 128
#define KD 1024
#define NT (KD / 64)            // 16 K-tiles for 256^2 kernel

typedef __attribute__((ext_vector_type(8))) short bf16x8;
typedef __attribute__((ext_vector_type(4))) float f32x4;

__device__ __forceinline__ ushort f2bf(float f) {
    union { float f; unsigned u; } v; v.f = f;
    unsigned u = v.u;
    u += 0x7fffu + ((u >> 16) & 1u);
    return (ushort)(u >> 16);
}
__device__ __forceinline__ float bf2f(ushort h) {
    union { unsigned u; float f; } v; v.u = ((unsigned)h) << 16;
    return v.f;
}

// ---------------------------------------------------------------------------
__global__ __launch_bounds__(256) void cvt_bf16x8(const float* __restrict__ in,
                                                  ushort* __restrict__ out,
                                                  int n8) {
    int i = blockIdx.x * blockDim.x + threadIdx.x;
    if (i >= n8) return;
    const float4* p = (const float4*)in;
    float4 a = p[2 * i], b = p[2 * i + 1];
    uint4 o;
    o.x = (unsigned)f2bf(a.x) | ((unsigned)f2bf(a.y) << 16);
    o.y = (unsigned)f2bf(a.z) | ((unsigned)f2bf(a.w) << 16);
    o.z = (unsigned)f2bf(b.x) | ((unsigned)f2bf(b.y) << 16);
    o.w = (unsigned)f2bf(b.z) | ((unsigned)f2bf(b.w) << 16);
    ((uint4*)out)[i] = o;
}

// ---------------------------------------------------------------------------
__global__ void transpose_cvt(const float* __restrict__ W,
                              ushort* __restrict__ Wt,
                              int Kd, int N, int Npad) {
    __shared__ float tile[32][33];
    int n0 = blockIdx.x * 32, k0 = blockIdx.y * 32;
    int tx = threadIdx.x, ty = threadIdx.y;
#pragma unroll
    for (int j = 0; j < 4; ++j) {
        int k = k0 + ty * 4 + j;
        int n = n0 + tx;
        tile[ty * 4 + j][tx] = (n < N) ? W[(size_t)k * N + n] : 0.f;
    }
    __syncthreads();
#pragma unroll
    for (int j = 0; j < 4; ++j) {
        int n = n0 + ty * 4 + j;
        if (n < Npad)
            Wt[(size_t)n * Kd + k0 + tx] = f2bf(tile[tx][ty * 4 + j]);
    }
}

// ---------------------------------------------------------------------------
// 256x256 bf16 MFMA GEMM, BK=64, 512 threads (8 waves 2Mx4N), dbuf LDS,
// counted-vmcnt pipeline + st_16x32 swizzle + setprio + XCD swizzle.
// Register-lean: single base addr per matrix (const-stride folding), frag
// reads as base + compile-time ds offsets, <=8 frags live across barrier.
// ---------------------------------------------------------------------------
#define MFMA_HALF(AF, BF, MOFF)                                               \
    __builtin_amdgcn_s_setprio(1);                                            \
    _Pragma("unroll")                                                         \
    for (int m = 0; m < 4; ++m)                                               \
        _Pragma("unroll")                                                     \
        for (int n = 0; n < 4; ++n)                                           \
            acc[m + MOFF][n] = __builtin_amdgcn_mfma_f32_16x16x32_bf16(       \
                AF[m], BF[n], acc[m + MOFF][n], 0, 0, 0);                     \
    __builtin_amdgcn_s_setprio(0);

template <bool OUT_BF16>
__global__ __launch_bounds__(512, 2) void gemm256(
    const ushort* __restrict__ A, const ushort* __restrict__ Bt,
    const float* __restrict__ bias, void* __restrict__ Cp, int ldc) {
    __shared__ ushort Ab[2][256 * 64];
    __shared__ ushort Bb[2][256 * 64];

    const int tid  = threadIdx.x;
    const int lane = tid & 63;
    const int wid  = tid >> 6;
    const int wr = wid >> 2;        // 0..1  (M half, 128 rows)
    const int wc = wid & 3;         // 0..3  (N quarter, 64 cols)
    const int fr = lane & 15;
    const int fq = lane >> 4;

    // bijective XCD swizzle: 256 wgs, 32 consecutive per XCD
    const int orig = blockIdx.x;
    const int nid  = (orig & 7) * 32 + (orig >> 3);
    const int bm = (nid >> 2) * 256;
    const int bn = (nid & 3) * 256;

    // --- staging: linear LDS dest + inverse-swizzled global src ---
    // chunk c = i*512 + wid*64 + lane; swizzle bit only depends on tid bit 5,
    // so the 4 chunks per lane differ by a constant row stride of 64.
    {
    }
    const int p0  = (tid * 16) ^ (((tid >> 5) & 1) << 5);  // byte in 64-row group
    const int r0  = p0 >> 7;                               // row 0..63
    const int kb0 = (p0 & 127) >> 1;                       // ushort col 0..63
    const size_t srcA0 = (size_t)(bm + r0) * KD + kb0;
    const size_t srcB0 = (size_t)(bn + r0) * KD + kb0;

    // --- read-side swizzled fragment bases (ushort offsets) ---
    // row = (half)*X + m*16 + fr; swizzle bit = fr bit2 only -> const offsets.
    const int swb = (((fq * 16) ^ (((fr >> 2) & 1) << 5)) >> 1);  // ushorts
    const int baseA0 = (wr * 128 + fr) * 64 + swb;
    const int baseB0 = (wc * 64 + fr) * 64 + swb;

    f32x4 acc[8][4];
#pragma unroll
    for (int m = 0; m < 8; ++m)
#pragma unroll
        for (int n = 0; n < 4; ++n) acc[m][n] = (f32x4){0.f, 0.f, 0.f, 0.f};

    auto stage = [&](int buf, int koff) {
        const ushort* Ap = A + srcA0 + koff;
        const ushort* Bp = Bt + srcB0 + koff;
#pragma unroll
        for (int i = 0; i < 4; ++i) {
            __builtin_amdgcn_global_load_lds(
                (const __attribute__((address_space(1))) void*)(Ap + (size_t)i * 64 * KD),
                (__attribute__((address_space(3))) void*)(&Ab[buf][(i * 512 + wid * 64) * 8]),
                16, 0, 0);
            __builtin_amdgcn_global_load_lds(
                (const __attribute__((address_space(1))) void*)(Bp + (size_t)i * 64 * KD),
                (__attribute__((address_space(3))) void*)(&Bb[buf][(i * 512 + wid * 64) * 8]),
                16, 0, 0);
        }
    };

    // prologue: tiles 0 and 1 in flight; wait only for tile 0
    stage(0, 0);
    stage(1, 64);
    asm volatile("s_waitcnt vmcnt(8)" ::: "memory");
    __builtin_amdgcn_sched_barrier(0);
    __builtin_amdgcn_s_barrier();

#pragma unroll 1
    for (int t = 0; t < NT; ++t) {
        const int cur = t & 1;
        const ushort* Ac = &Ab[cur][0];
        const ushort* Bc = &Bb[cur][0];

        // ---- ksub0: two M-half phases sharing b0 ----
        {
            bf16x8 b0[4], aA[4];
#pragma unroll
            for (int n = 0; n < 4; ++n)
                b0[n] = *(const bf16x8*)(Bc + baseB0 + n * 1024);
#pragma unroll
            for (int m = 0; m < 4; ++m)
                aA[m] = *(const bf16x8*)(Ac + baseA0 + m * 1024);
            MFMA_HALF(aA, b0, 0)
#pragma unroll
            for (int m = 0; m < 4; ++m)
                aA[m] = *(const bf16x8*)(Ac + baseA0 + (m + 4) * 1024);
            MFMA_HALF(aA, b0, 4)
        }

        // ---- ksub1: finish M-half 0 BEFORE the barrier; only b1+cB cross ----
        bf16x8 b1[4], cB[4];
        {
            bf16x8 cA[4];
#pragma unroll
            for (int n = 0; n < 4; ++n)
                b1[n] = *(const bf16x8*)(Bc + baseB0 + n * 1024 + 32);
#pragma unroll
            for (int m = 0; m < 4; ++m)
                cA[m] = *(const bf16x8*)(Ac + baseA0 + m * 1024 + 32);
            MFMA_HALF(cA, b1, 0)
        }
#pragma unroll
        for (int m = 0; m < 4; ++m)
            cB[m] = *(const bf16x8*)(Ac + baseA0 + (m + 4) * 1024 + 32);

        if (t < NT - 1) {
            // all ds_reads of buf[cur] complete -> safe to overwrite
            asm volatile("s_waitcnt lgkmcnt(0)" ::: "memory");
            __builtin_amdgcn_sched_barrier(0);
            __builtin_amdgcn_s_barrier();
            if (t < NT - 2) stage(cur, (t + 2) * 64);

            MFMA_HALF(cB, b1, 4)

            if (t < NT - 2) {
                asm volatile("s_waitcnt vmcnt(8)" ::: "memory");  // tile t+1 landed
            } else {
                asm volatile("s_waitcnt vmcnt(0)" ::: "memory");
            }
            __builtin_amdgcn_sched_barrier(0);
            __builtin_amdgcn_s_barrier();
        } else {
            MFMA_HALF(cB, b1, 4)
        }
    }

    // epilogue: C/D layout col=lane&15, row=(lane>>4)*4+r
#pragma unroll
    for (int n = 0; n < 4; ++n) {
        int col = bn + wc * 64 + n * 16 + fr;
        float bv = bias[col];
#pragma unroll
        for (int m = 0; m < 8; ++m) {
#pragma unroll
            for (int r = 0; r < 4; ++r) {
                int row = bm + wr * 128 + m * 16 + fq * 4 + r;
                float v = acc[m][n][r] + bv;
                if (OUT_BF16)
                    ((ushort*)Cp)[(size_t)row * ldc + col] = f2bf(v);
                else
                    ((float*)Cp)[(size_t)row * ldc + col] = v;
            }
        }
    }
}

// ---------------------------------------------------------------------------
// m97-style 128x128 GEMM for the small N=112 GEMM2
// ---------------------------------------------------------------------------
template <bool OUT_BF16, bool NGUARD>
__global__ __launch_bounds__(256) void gemm_mfma(const ushort* __restrict__ A,
                                                 const ushort* __restrict__ Bt,
                                                 const float* __restrict__ bias,
                                                 void* __restrict__ Cp,
                                                 int Kd, int N, int ldc) {
    __shared__ ushort Als[128 * 32];
    __shared__ ushort Bls[128 * 32];
    const int tid  = threadIdx.x;
    const int lane = tid & 63;
    const int wid  = tid >> 6;
    const int wr = wid >> 1, wc = wid & 1;
    const int bm = blockIdx.y * 128, bn = blockIdx.x * 128;
    const int fq = lane >> 4, fr = lane & 15;

    f32x4 acc[4][4];
#pragma unroll
    for (int m = 0; m < 4; ++m)
#pragma unroll
        for (int n = 0; n < 4; ++n) acc[m][n] = (f32x4){0.f, 0.f, 0.f, 0.f};

    const int c0 = wid * 128 + lane;
    const int c1 = c0 + 64;
    const int r0 = c0 >> 2, o0 = (c0 & 3) * 8;
    const int r1 = c1 >> 2, o1 = (c1 & 3) * 8;

    for (int k0 = 0; k0 < Kd; k0 += 32) {
        __builtin_amdgcn_global_load_lds(
            (const __attribute__((address_space(1))) void*)&A[(size_t)(bm + r0) * Kd + k0 + o0],
            (__attribute__((address_space(3))) void*)&Als[(wid * 2 + 0) * 512], 16, 0, 0);
        __builtin_amdgcn_global_load_lds(
            (const __attribute__((address_space(1))) void*)&A[(size_t)(bm + r1) * Kd + k0 + o1],
            (__attribute__((address_space(3))) void*)&Als[(wid * 2 + 1) * 512], 16, 0, 0);
        __builtin_amdgcn_global_load_lds(
            (const __attribute__((address_space(1))) void*)&Bt[(size_t)(bn + r0) * Kd + k0 + o0],
            (__attribute__((address_space(3))) void*)&Bls[(wid * 2 + 0) * 512], 16, 0, 0);
        __builtin_amdgcn_global_load_lds(
            (const __attribute__((address_space(1))) void*)&Bt[(size_t)(bn + r1) * Kd + k0 + o1],
            (__attribute__((address_space(3))) void*)&Bls[(wid * 2 + 1) * 512], 16, 0, 0);
        __syncthreads();

        bf16x8 af[4], bfr[4];
#pragma unroll
        for (int m = 0; m < 4; ++m)
            af[m] = *(const bf16x8*)&Als[(wr * 64 + m * 16 + fr) * 32 + fq * 8];
#pragma unroll
        for (int n = 0; n < 4; ++n)
            bfr[n] = *(const bf16x8*)&Bls[(wc * 64 + n * 16 + fr) * 32 + fq * 8];
#pragma unroll
        for (int m = 0; m < 4; ++m)
#pragma unroll
            for (int n = 0; n < 4; ++n)
                acc[m][n] = __builtin_amdgcn_mfma_f32_16x16x32_bf16(
                    af[m], bfr[n], acc[m][n], 0, 0, 0);
        __syncthreads();
    }

#pragma unroll
    for (int m = 0; m < 4; ++m) {
#pragma unroll
        for (int n = 0; n < 4; ++n) {
            int col = bn + wc * 64 + n * 16 + fr;
            if (NGUARD && col >= N) continue;
            float bv = bias[col];
#pragma unroll
            for (int r = 0; r < 4; ++r) {
                int row = bm + wr * 64 + m * 16 + fq * 4 + r;
                float v = acc[m][n][r] + bv;
                if (OUT_BF16)
                    ((ushort*)Cp)[(size_t)row * ldc + col] = f2bf(v);
                else
                    ((float*)Cp)[(size_t)row * ldc + col] = v;
            }
        }
    }
}

// ---------------------------------------------------------------------------
// Dynamic conv with fused per-head softmax over the 7 taps.
// ---------------------------------------------------------------------------
__global__ __launch_bounds__(256) void dynconv_bf16(const ushort* __restrict__ h,
                                                    const float* __restrict__ q,
                                                    const float* __restrict__ cbias,
                                                    ushort* __restrict__ out) {
    const int m = blockIdx.x;
    const int t = m >> 4;
    const int b = m & 15;

    __shared__ float wsm[HK];
    if (threadIdx.x < HK)
        wsm[threadIdx.x] = q[(size_t)m * HK + threadIdx.x];
    __syncthreads();
    if (threadIdx.x < H_DIM) {
        float* p = &wsm[threadIdx.x * K_TAPS];
        float mx = p[0];
#pragma unroll
        for (int k = 1; k < K_TAPS; ++k) mx = fmaxf(mx, p[k]);
        float e[K_TAPS], s = 0.f;
#pragma unroll
        for (int k = 0; k < K_TAPS; ++k) { e[k] = __expf(p[k] - mx); s += e[k]; }
        float inv = 1.f / s;
#pragma unroll
        for (int k = 0; k < K_TAPS; ++k) p[k] = e[k] * inv;
    }
    __syncthreads();

    const int c = threadIdx.x * 4;
    const int hh = c >> 6;

    float4 bias = *(const float4*)&cbias[c];
    float a0 = bias.x, a1 = bias.y, a2 = bias.z, a3 = bias.w;

#pragma unroll
    for (int k = 0; k < K_TAPS; ++k) {
        int tt = t + k - PAD_LEFT;
        if (tt < 0 || tt >= T_DIM) continue;
        ushort4 hv = *(const ushort4*)&h[((size_t)tt * B_DIM + b) * C_DIM + c];
        float wk = wsm[hh * K_TAPS + k];
        a0 = fmaf(bf2f(hv.x), wk, a0);
        a1 = fmaf(bf2f(hv.y), wk, a1);
        a2 = fmaf(bf2f(hv.z), wk, a2);
        a3 = fmaf(bf2f(hv.w), wk, a3);
    }
    ushort4 o;
    o.x = f2bf(a0); o.y = f2bf(a1); o.z = f2bf(a2); o.w = f2bf(a3);
    *(ushort4*)&out[(size_t)m * C_DIM + c] = o;
}

// ---------------------------------------------------------------------------
extern "C" void kernel_launch(void* const* d_in, const int* in_sizes, int n_in,
                              void* d_out, int out_size, void* d_ws,
                              size_t ws_size, hipStream_t stream) {
    const float* x     = (const float*)d_in[0];
    const float* W1    = (const float*)d_in[1];
    const float* b1    = (const float*)d_in[2];
    const float* Wq    = (const float*)d_in[3];
    const float* bq    = (const float*)d_in[4];
    const float* cbias = (const float*)d_in[5];
    const float* W2    = (const float*)d_in[6];
    const float* b2    = (const float*)d_in[7];
    float* out = (float*)d_out;

    ushort* xb    = (ushort*)d_ws;
    ushort* hb    = xb    + (size_t)M_DIM * C_DIM;
    ushort* convb = hb    + (size_t)M_DIM * C_DIM;
    ushort* W1t   = convb + (size_t)M_DIM * C_DIM;
    ushort* W2t   = W1t   + (size_t)C_DIM * C_DIM;
    ushort* Wqt   = W2t   + (size_t)C_DIM * OUT_DIM;
    float*  q     = (float*)(Wqt + (size_t)HKP * C_DIM);

    cvt_bf16x8<<<dim3(M_DIM * C_DIM / 8 / 256), dim3(256), 0, stream>>>(
        x, xb, M_DIM * C_DIM / 8);
    transpose_cvt<<<dim3(C_DIM / 32, C_DIM / 32), dim3(32, 8), 0, stream>>>(
        W1, W1t, C_DIM, C_DIM, C_DIM);
    transpose_cvt<<<dim3(HKP / 32, C_DIM / 32), dim3(32, 8), 0, stream>>>(
        Wq, Wqt, C_DIM, HK, HKP);
    transpose_cvt<<<dim3(OUT_DIM / 32, C_DIM / 32), dim3(32, 8), 0, stream>>>(
        W2, W2t, C_DIM, OUT_DIM, OUT_DIM);

    // 1) h = bf16(x @ W1 + b1)
    gemm256<true><<<dim3(256), dim3(512), 0, stream>>>(xb, W1t, b1, hb, C_DIM);

    // 2) q = h @ Wq + bq   [16384 x 112]
    gemm_mfma<false, true>
        <<<dim3(1, M_DIM / 128), dim3(256), 0, stream>>>(
            hb, Wqt, bq, q, C_DIM, HK, HK);

    // 3+4) conv = bf16(dynconv(h, softmax(q)) + conv_bias)
    dynconv_bf16<<<dim3(M_DIM), dim3(256), 0, stream>>>(hb, q, cbias, convb);

    // 5) out = conv @ W2 + b2
    gemm256<false><<<dim3(256), dim3(512), 0, stream>>>(convb, W2t, b2, out,
                                                        OUT_DIM);
}

// Round 6
// 162.595 us; speedup vs baseline: 2.9905x; 1.0123x over previous
//
#include <hip/hip_runtime.h>
#include <math.h>

#define T_DIM 1024
#define B_DIM 16
#define C_DIM 1024
#define H_DIM 16
#define K_TAPS 7
#define PAD_LEFT 3
#define OUT_DIM 1024
#define M_DIM (T_DIM * B_DIM)   // 16384
#define HK 112
#define HKP 128
#define KD 1024
#define NT (KD / 64)            // 16 K-tiles for 256^2 kernel

typedef __attribute__((ext_vector_type(8))) short bf16x8;
typedef __attribute__((ext_vector_type(4))) float f32x4;

__device__ __forceinline__ ushort f2bf(float f) {
    union { float f; unsigned u; } v; v.f = f;
    unsigned u = v.u;
    u += 0x7fffu + ((u >> 16) & 1u);
    return (ushort)(u >> 16);
}
__device__ __forceinline__ float bf2f(ushort h) {
    union { unsigned u; float f; } v; v.u = ((unsigned)h) << 16;
    return v.f;
}

// ---------------------------------------------------------------------------
__global__ __launch_bounds__(256) void cvt_bf16x8(const float* __restrict__ in,
                                                  ushort* __restrict__ out,
                                                  int n8) {
    int i = blockIdx.x * blockDim.x + threadIdx.x;
    if (i >= n8) return;
    const float4* p = (const float4*)in;
    float4 a = p[2 * i], b = p[2 * i + 1];
    uint4 o;
    o.x = (unsigned)f2bf(a.x) | ((unsigned)f2bf(a.y) << 16);
    o.y = (unsigned)f2bf(a.z) | ((unsigned)f2bf(a.w) << 16);
    o.z = (unsigned)f2bf(b.x) | ((unsigned)f2bf(b.y) << 16);
    o.w = (unsigned)f2bf(b.z) | ((unsigned)f2bf(b.w) << 16);
    ((uint4*)out)[i] = o;
}

// ---------------------------------------------------------------------------
__global__ void transpose_cvt(const float* __restrict__ W,
                              ushort* __restrict__ Wt,
                              int Kd, int N, int Npad) {
    __shared__ float tile[32][33];
    int n0 = blockIdx.x * 32, k0 = blockIdx.y * 32;
    int tx = threadIdx.x, ty = threadIdx.y;
#pragma unroll
    for (int j = 0; j < 4; ++j) {
        int k = k0 + ty * 4 + j;
        int n = n0 + tx;
        tile[ty * 4 + j][tx] = (n < N) ? W[(size_t)k * N + n] : 0.f;
    }
    __syncthreads();
#pragma unroll
    for (int j = 0; j < 4; ++j) {
        int n = n0 + ty * 4 + j;
        if (n < Npad)
            Wt[(size_t)n * Kd + k0 + tx] = f2bf(tile[tx][ty * 4 + j]);
    }
}

// ---------------------------------------------------------------------------
// 256x256 bf16 MFMA GEMM, BK=64, 512 threads (8 waves 2Mx4N), dbuf LDS,
// counted-vmcnt pipeline + 3-bit XOR swizzle (byte ^= (row&7)<<4) + setprio
// + XCD swizzle. Register-lean const-stride addressing (no spill).
// ---------------------------------------------------------------------------
#define MFMA_HALF(AF, BF, MOFF)                                               \
    __builtin_amdgcn_s_setprio(1);                                            \
    _Pragma("unroll")                                                         \
    for (int m = 0; m < 4; ++m)                                               \
        _Pragma("unroll")                                                     \
        for (int n = 0; n < 4; ++n)                                           \
            acc[m + MOFF][n] = __builtin_amdgcn_mfma_f32_16x16x32_bf16(       \
                AF[m], BF[n], acc[m + MOFF][n], 0, 0, 0);                     \
    __builtin_amdgcn_s_setprio(0);

template <bool OUT_BF16>
__global__ __launch_bounds__(512, 2) void gemm256(
    const ushort* __restrict__ A, const ushort* __restrict__ Bt,
    const float* __restrict__ bias, void* __restrict__ Cp, int ldc) {
    __shared__ ushort Ab[2][256 * 64];
    __shared__ ushort Bb[2][256 * 64];

    const int tid  = threadIdx.x;
    const int lane = tid & 63;
    const int wid  = tid >> 6;
    const int wr = wid >> 2;        // 0..1  (M half, 128 rows)
    const int wc = wid & 3;         // 0..3  (N quarter, 64 cols)
    const int fr = lane & 15;
    const int fq = lane >> 4;

    // bijective XCD swizzle: 256 wgs, 32 consecutive per XCD
    const int orig = blockIdx.x;
    const int nid  = (orig & 7) * 32 + (orig >> 3);
    const int bm = (nid >> 2) * 256;
    const int bn = (nid & 3) * 256;

    // --- staging: linear LDS dest + inverse-swizzled global src ---
    // LDS byte p holds global[row = p>>7][ (p&127) ^ ((row&7)<<4) ].
    // chunk per lane: p = tid*16 (+ i*512*16); row&7 invariant across i.
    const int r0  = tid >> 3;                              // row 0..63
    const int kb0 = ((tid & 7) ^ (r0 & 7)) * 8;            // ushort col
    const size_t srcA0 = (size_t)(bm + r0) * KD + kb0;
    const size_t srcB0 = (size_t)(bn + r0) * KD + kb0;

    // --- read-side swizzled fragment bases (ushort offsets) ---
    // col(ushort) = fq*8 + ksub*32, XOR mask (fr&7)<<3 (bits 3-5).
    const int swb = (fq * 8) ^ ((fr & 7) << 3);
    const int baseA0 = (wr * 128 + fr) * 64 + swb;   // ksub0
    const int baseB0 = (wc * 64 + fr) * 64 + swb;
    const int baseA1 = baseA0 ^ 32;                  // ksub1 (+64B under XOR)
    const int baseB1 = baseB0 ^ 32;

    f32x4 acc[8][4];
#pragma unroll
    for (int m = 0; m < 8; ++m)
#pragma unroll
        for (int n = 0; n < 4; ++n) acc[m][n] = (f32x4){0.f, 0.f, 0.f, 0.f};

    auto stage = [&](int buf, int koff) {
        const ushort* Ap = A + srcA0 + koff;
        const ushort* Bp = Bt + srcB0 + koff;
#pragma unroll
        for (int i = 0; i < 4; ++i) {
            __builtin_amdgcn_global_load_lds(
                (const __attribute__((address_space(1))) void*)(Ap + (size_t)i * 64 * KD),
                (__attribute__((address_space(3))) void*)(&Ab[buf][(i * 512 + wid * 64) * 8]),
                16, 0, 0);
            __builtin_amdgcn_global_load_lds(
                (const __attribute__((address_space(1))) void*)(Bp + (size_t)i * 64 * KD),
                (__attribute__((address_space(3))) void*)(&Bb[buf][(i * 512 + wid * 64) * 8]),
                16, 0, 0);
        }
    };

    // prologue: tiles 0 and 1 in flight; wait only for tile 0
    stage(0, 0);
    stage(1, 64);
    asm volatile("s_waitcnt vmcnt(8)" ::: "memory");
    __builtin_amdgcn_sched_barrier(0);
    __builtin_amdgcn_s_barrier();

#pragma unroll 1
    for (int t = 0; t < NT; ++t) {
        const int cur = t & 1;
        const ushort* Ac = &Ab[cur][0];
        const ushort* Bc = &Bb[cur][0];

        // ---- ksub0: two M-half phases sharing b0 ----
        {
            bf16x8 b0[4], aA[4];
#pragma unroll
            for (int n = 0; n < 4; ++n)
                b0[n] = *(const bf16x8*)(Bc + baseB0 + n * 1024);
#pragma unroll
            for (int m = 0; m < 4; ++m)
                aA[m] = *(const bf16x8*)(Ac + baseA0 + m * 1024);
            MFMA_HALF(aA, b0, 0)
#pragma unroll
            for (int m = 0; m < 4; ++m)
                aA[m] = *(const bf16x8*)(Ac + baseA0 + (m + 4) * 1024);
            MFMA_HALF(aA, b0, 4)
        }

        // ---- ksub1: finish M-half 0 BEFORE the barrier; only b1+cB cross ----
        bf16x8 b1[4], cB[4];
        {
            bf16x8 cA[4];
#pragma unroll
            for (int n = 0; n < 4; ++n)
                b1[n] = *(const bf16x8*)(Bc + baseB1 + n * 1024);
#pragma unroll
            for (int m = 0; m < 4; ++m)
                cA[m] = *(const bf16x8*)(Ac + baseA1 + m * 1024);
            MFMA_HALF(cA, b1, 0)
        }
#pragma unroll
        for (int m = 0; m < 4; ++m)
            cB[m] = *(const bf16x8*)(Ac + baseA1 + (m + 4) * 1024);

        if (t < NT - 1) {
            // all ds_reads of buf[cur] complete -> safe to overwrite
            asm volatile("s_waitcnt lgkmcnt(0)" ::: "memory");
            __builtin_amdgcn_sched_barrier(0);
            __builtin_amdgcn_s_barrier();
            if (t < NT - 2) stage(cur, (t + 2) * 64);

            MFMA_HALF(cB, b1, 4)

            if (t < NT - 2) {
                asm volatile("s_waitcnt vmcnt(8)" ::: "memory");  // tile t+1 landed
            } else {
                asm volatile("s_waitcnt vmcnt(0)" ::: "memory");
            }
            __builtin_amdgcn_sched_barrier(0);
            __builtin_amdgcn_s_barrier();
        } else {
            MFMA_HALF(cB, b1, 4)
        }
    }

    // epilogue: C/D layout col=lane&15, row=(lane>>4)*4+r
#pragma unroll
    for (int n = 0; n < 4; ++n) {
        int col = bn + wc * 64 + n * 16 + fr;
        float bv = bias[col];
#pragma unroll
        for (int m = 0; m < 8; ++m) {
#pragma unroll
            for (int r = 0; r < 4; ++r) {
                int row = bm + wr * 128 + m * 16 + fq * 4 + r;
                float v = acc[m][n][r] + bv;
                if (OUT_BF16)
                    ((ushort*)Cp)[(size_t)row * ldc + col] = f2bf(v);
                else
                    ((float*)Cp)[(size_t)row * ldc + col] = v;
            }
        }
    }
}

// ---------------------------------------------------------------------------
// m97-style 128x128 GEMM for the small N=112 GEMM2
// ---------------------------------------------------------------------------
template <bool OUT_BF16, bool NGUARD>
__global__ __launch_bounds__(256) void gemm_mfma(const ushort* __restrict__ A,
                                                 const ushort* __restrict__ Bt,
                                                 const float* __restrict__ bias,
                                                 void* __restrict__ Cp,
                                                 int Kd, int N, int ldc) {
    __shared__ ushort Als[128 * 32];
    __shared__ ushort Bls[128 * 32];
    const int tid  = threadIdx.x;
    const int lane = tid & 63;
    const int wid  = tid >> 6;
    const int wr = wid >> 1, wc = wid & 1;
    const int bm = blockIdx.y * 128, bn = blockIdx.x * 128;
    const int fq = lane >> 4, fr = lane & 15;

    f32x4 acc[4][4];
#pragma unroll
    for (int m = 0; m < 4; ++m)
#pragma unroll
        for (int n = 0; n < 4; ++n) acc[m][n] = (f32x4){0.f, 0.f, 0.f, 0.f};

    const int c0 = wid * 128 + lane;
    const int c1 = c0 + 64;
    const int r0 = c0 >> 2, o0 = (c0 & 3) * 8;
    const int r1 = c1 >> 2, o1 = (c1 & 3) * 8;

    for (int k0 = 0; k0 < Kd; k0 += 32) {
        __builtin_amdgcn_global_load_lds(
            (const __attribute__((address_space(1))) void*)&A[(size_t)(bm + r0) * Kd + k0 + o0],
            (__attribute__((address_space(3))) void*)&Als[(wid * 2 + 0) * 512], 16, 0, 0);
        __builtin_amdgcn_global_load_lds(
            (const __attribute__((address_space(1))) void*)&A[(size_t)(bm + r1) * Kd + k0 + o1],
            (__attribute__((address_space(3))) void*)&Als[(wid * 2 + 1) * 512], 16, 0, 0);
        __builtin_amdgcn_global_load_lds(
            (const __attribute__((address_space(1))) void*)&Bt[(size_t)(bn + r0) * Kd + k0 + o0],
            (__attribute__((address_space(3))) void*)&Bls[(wid * 2 + 0) * 512], 16, 0, 0);
        __builtin_amdgcn_global_load_lds(
            (const __attribute__((address_space(1))) void*)&Bt[(size_t)(bn + r1) * Kd + k0 + o1],
            (__attribute__((address_space(3))) void*)&Bls[(wid * 2 + 1) * 512], 16, 0, 0);
        __syncthreads();

        bf16x8 af[4], bfr[4];
#pragma unroll
        for (int m = 0; m < 4; ++m)
            af[m] = *(const bf16x8*)&Als[(wr * 64 + m * 16 + fr) * 32 + fq * 8];
#pragma unroll
        for (int n = 0; n < 4; ++n)
            bfr[n] = *(const bf16x8*)&Bls[(wc * 64 + n * 16 + fr) * 32 + fq * 8];
#pragma unroll
        for (int m = 0; m < 4; ++m)
#pragma unroll
            for (int n = 0; n < 4; ++n)
                acc[m][n] = __builtin_amdgcn_mfma_f32_16x16x32_bf16(
                    af[m], bfr[n], acc[m][n], 0, 0, 0);
        __syncthreads();
    }

#pragma unroll
    for (int m = 0; m < 4; ++m) {
#pragma unroll
        for (int n = 0; n < 4; ++n) {
            int col = bn + wc * 64 + n * 16 + fr;
            if (NGUARD && col >= N) continue;
            float bv = bias[col];
#pragma unroll
            for (int r = 0; r < 4; ++r) {
                int row = bm + wr * 64 + m * 16 + fq * 4 + r;
                float v = acc[m][n][r] + bv;
                if (OUT_BF16)
                    ((ushort*)Cp)[(size_t)row * ldc + col] = f2bf(v);
                else
                    ((float*)Cp)[(size_t)row * ldc + col] = v;
            }
        }
    }
}

// ---------------------------------------------------------------------------
// Dynamic conv with fused per-head softmax over the 7 taps.
// ---------------------------------------------------------------------------
__global__ __launch_bounds__(256) void dynconv_bf16(const ushort* __restrict__ h,
                                                    const float* __restrict__ q,
                                                    const float* __restrict__ cbias,
                                                    ushort* __restrict__ out) {
    const int m = blockIdx.x;
    const int t = m >> 4;
    const int b = m & 15;

    __shared__ float wsm[HK];
    if (threadIdx.x < HK)
        wsm[threadIdx.x] = q[(size_t)m * HK + threadIdx.x];
    __syncthreads();
    if (threadIdx.x < H_DIM) {
        float* p = &wsm[threadIdx.x * K_TAPS];
        float mx = p[0];
#pragma unroll
        for (int k = 1; k < K_TAPS; ++k) mx = fmaxf(mx, p[k]);
        float e[K_TAPS], s = 0.f;
#pragma unroll
        for (int k = 0; k < K_TAPS; ++k) { e[k] = __expf(p[k] - mx); s += e[k]; }
        float inv = 1.f / s;
#pragma unroll
        for (int k = 0; k < K_TAPS; ++k) p[k] = e[k] * inv;
    }
    __syncthreads();

    const int c = threadIdx.x * 4;
    const int hh = c >> 6;

    float4 bias = *(const float4*)&cbias[c];
    float a0 = bias.x, a1 = bias.y, a2 = bias.z, a3 = bias.w;

#pragma unroll
    for (int k = 0; k < K_TAPS; ++k) {
        int tt = t + k - PAD_LEFT;
        if (tt < 0 || tt >= T_DIM) continue;
        ushort4 hv = *(const ushort4*)&h[((size_t)tt * B_DIM + b) * C_DIM + c];
        float wk = wsm[hh * K_TAPS + k];
        a0 = fmaf(bf2f(hv.x), wk, a0);
        a1 = fmaf(bf2f(hv.y), wk, a1);
        a2 = fmaf(bf2f(hv.z), wk, a2);
        a3 = fmaf(bf2f(hv.w), wk, a3);
    }
    ushort4 o;
    o.x = f2bf(a0); o.y = f2bf(a1); o.z = f2bf(a2); o.w = f2bf(a3);
    *(ushort4*)&out[(size_t)m * C_DIM + c] = o;
}

// ---------------------------------------------------------------------------
extern "C" void kernel_launch(void* const* d_in, const int* in_sizes, int n_in,
                              void* d_out, int out_size, void* d_ws,
                              size_t ws_size, hipStream_t stream) {
    const float* x     = (const float*)d_in[0];
    const float* W1    = (const float*)d_in[1];
    const float* b1    = (const float*)d_in[2];
    const float* Wq    = (const float*)d_in[3];
    const float* bq    = (const float*)d_in[4];
    const float* cbias = (const float*)d_in[5];
    const float* W2    = (const float*)d_in[6];
    const float* b2    = (const float*)d_in[7];
    float* out = (float*)d_out;

    ushort* xb    = (ushort*)d_ws;
    ushort* hb    = xb    + (size_t)M_DIM * C_DIM;
    ushort* convb = hb    + (size_t)M_DIM * C_DIM;
    ushort* W1t   = convb + (size_t)M_DIM * C_DIM;
    ushort* W2t   = W1t   + (size_t)C_DIM * C_DIM;
    ushort* Wqt   = W2t   + (size_t)C_DIM * OUT_DIM;
    float*  q     = (float*)(Wqt + (size_t)HKP * C_DIM);

    cvt_bf16x8<<<dim3(M_DIM * C_DIM / 8 / 256), dim3(256), 0, stream>>>(
        x, xb, M_DIM * C_DIM / 8);
    transpose_cvt<<<dim3(C_DIM / 32, C_DIM / 32), dim3(32, 8), 0, stream>>>(
        W1, W1t, C_DIM, C_DIM, C_DIM);
    transpose_cvt<<<dim3(HKP / 32, C_DIM / 32), dim3(32, 8), 0, stream>>>(
        Wq, Wqt, C_DIM, HK, HKP);
    transpose_cvt<<<dim3(OUT_DIM / 32, C_DIM / 32), dim3(32, 8), 0, stream>>>(
        W2, W2t, C_DIM, OUT_DIM, OUT_DIM);

    // 1) h = bf16(x @ W1 + b1)
    gemm256<true><<<dim3(256), dim3(512), 0, stream>>>(xb, W1t, b1, hb, C_DIM);

    // 2) q = h @ Wq + bq   [16384 x 112]
    gemm_mfma<false, true>
        <<<dim3(1, M_DIM / 128), dim3(256), 0, stream>>>(
            hb, Wqt, bq, q, C_DIM, HK, HK);

    // 3+4) conv = bf16(dynconv(h, softmax(q)) + conv_bias)
    dynconv_bf16<<<dim3(M_DIM), dim3(256), 0, stream>>>(hb, q, cbias, convb);

    // 5) out = conv @ W2 + b2
    gemm256<false><<<dim3(256), dim3(512), 0, stream>>>(convb, W2t, b2, out,
                                                        OUT_DIM);
}